// Round 1
// baseline (544.467 us; speedup 1.0000x reference)
//
#include <hip/hip_runtime.h>
#include <math.h>

// Problem: B=4, S=2048, D=1024, H=16, DK=64.
// out = softmax((q Wq^T)(k Wk^T)^T / 8) (v Wv^T) Wo^T, heads split on D.
//
// Pipeline:
//   1. cast fp32->bf16: q,k,v, Wq,Wk,Wv,Wo              (ws)
//   2. gemm_qkv: Qp=q@Wq^T, Kp=k@Wk^T (bf16 [8192,1024]),
//                VpT = (v@Wv^T) stored transposed [B*1024, 2048] bf16
//   3. attn: flash attention per (b,h), Q-tile 64, K-tile 64 -> Xp bf16
//   4. gemm_out: out = Xp @ Wo^T  (fp32)

#define DEV __device__ __forceinline__

typedef __bf16 bf16x8 __attribute__((ext_vector_type(8)));
typedef float f32x4 __attribute__((ext_vector_type(4)));

typedef __attribute__((address_space(1))) const unsigned int g_u32;
typedef __attribute__((address_space(3))) unsigned int l_u32;

constexpr int BB = 4, SS = 2048, DD = 1024, HH = 16;  // DK = 64

DEV unsigned short f2bf(float x) {  // RNE truncate to bf16
  unsigned int u = __float_as_uint(x);
  u += 0x7fffu + ((u >> 16) & 1u);
  return (unsigned short)(u >> 16);
}

DEV void ld16(const unsigned short* g, unsigned short* l) {
  // async global->LDS, 16B per lane; LDS dest = wave-uniform base + lane*16
  __builtin_amdgcn_global_load_lds((g_u32*)g, (l_u32*)l, 16, 0, 0);
}

__global__ __launch_bounds__(256) void cast_f32_bf16(
    const float* __restrict__ src, unsigned short* __restrict__ dst, int n4) {
  int i = blockIdx.x * 256 + threadIdx.x;
  if (i < n4) {
    float4 v = reinterpret_cast<const float4*>(src)[i];
    ushort4 o;
    o.x = f2bf(v.x); o.y = f2bf(v.y); o.z = f2bf(v.z); o.w = f2bf(v.w);
    reinterpret_cast<ushort4*>(dst)[i] = o;
  }
}

// ---- NT GEMM core: C[128x128] tile, A [M,1024] bf16 rm, W [N,1024] bf16 rm.
// 4 waves, each 64x64 (4x4 MFMA tiles of 16x16x32 bf16). BK=32.
DEV void gemm_core(const unsigned short* __restrict__ A,
                   const unsigned short* __restrict__ W,
                   unsigned short* As, unsigned short* Bs,
                   f32x4 (&acc)[4][4], int tileM, int tileN) {
  const int tid = threadIdx.x;
  const int w = tid >> 6, lane = tid & 63;
  const int wr = (w & 1) * 64, wc = (w >> 1) * 64;
  const int l15 = lane & 15, g4 = lane >> 4;
  const int srow = lane >> 2;        // staging: 4 lanes per 32-elem row
  const int scol = (lane & 3) * 8;

  const f32x4 fzero = {0.f, 0.f, 0.f, 0.f};
#pragma unroll
  for (int i = 0; i < 4; i++)
#pragma unroll
    for (int j = 0; j < 4; j++) acc[i][j] = fzero;

  for (int k0 = 0; k0 < 1024; k0 += 32) {
#pragma unroll
    for (int j = 0; j < 2; ++j) {
      int c = w * 2 + j;  // chunk: 16 rows x 64B = 1024B
      ld16(A + (size_t)(tileM + c * 16 + srow) * 1024 + k0 + scol, As + c * 512);
      ld16(W + (size_t)(tileN + c * 16 + srow) * 1024 + k0 + scol, Bs + c * 512);
    }
    __syncthreads();
    bf16x8 aF[4], bF[4];
#pragma unroll
    for (int i = 0; i < 4; i++)
      aF[i] = *reinterpret_cast<const bf16x8*>(&As[(wr + i * 16 + l15) * 32 + g4 * 8]);
#pragma unroll
    for (int j = 0; j < 4; j++)
      bF[j] = *reinterpret_cast<const bf16x8*>(&Bs[(wc + j * 16 + l15) * 32 + g4 * 8]);
#pragma unroll
    for (int i = 0; i < 4; i++)
#pragma unroll
      for (int j = 0; j < 4; j++)
        acc[i][j] = __builtin_amdgcn_mfma_f32_16x16x32_bf16(aF[i], bF[j], acc[i][j], 0, 0, 0);
    __syncthreads();
  }
}

__global__ __launch_bounds__(256) void gemm_qkv(
    const unsigned short* __restrict__ qb, const unsigned short* __restrict__ kb,
    const unsigned short* __restrict__ vb, const unsigned short* __restrict__ Wq,
    const unsigned short* __restrict__ Wk, const unsigned short* __restrict__ Wv,
    unsigned short* __restrict__ Qp, unsigned short* __restrict__ Kp,
    unsigned short* __restrict__ VpT) {
  __shared__ __align__(16) unsigned short As[128 * 32];
  __shared__ __align__(16) unsigned short Bs[128 * 32];
  const int z = blockIdx.z;
  const unsigned short* A = (z == 0) ? qb : (z == 1) ? kb : vb;
  const unsigned short* W = (z == 0) ? Wq : (z == 1) ? Wk : Wv;
  const int tileM = blockIdx.x * 128, tileN = blockIdx.y * 128;
  f32x4 acc[4][4];
  gemm_core(A, W, As, Bs, acc, tileM, tileN);

  const int tid = threadIdx.x, w = tid >> 6, lane = tid & 63;
  const int wr = (w & 1) * 64, wc = (w >> 1) * 64;
  const int l15 = lane & 15, g4 = lane >> 4;
  if (z < 2) {
    unsigned short* C = (z == 0) ? Qp : Kp;
#pragma unroll
    for (int i = 0; i < 4; i++)
#pragma unroll
      for (int j = 0; j < 4; j++) {
        int col = tileN + wc + j * 16 + l15;
#pragma unroll
        for (int r = 0; r < 4; r++) {
          int row = tileM + wr + i * 16 + g4 * 4 + r;
          C[(size_t)row * 1024 + col] = f2bf(acc[i][j][r]);
        }
      }
  } else {
    // transposed store: VpT[(b*1024 + col)*2048 + s], 4 contiguous s per lane
    const int b = tileM / 2048, s0 = tileM % 2048;
#pragma unroll
    for (int i = 0; i < 4; i++)
#pragma unroll
      for (int j = 0; j < 4; j++) {
        int col = tileN + wc + j * 16 + l15;
        int s = s0 + wr + i * 16 + g4 * 4;
        ushort4 pk;
        pk.x = f2bf(acc[i][j][0]); pk.y = f2bf(acc[i][j][1]);
        pk.z = f2bf(acc[i][j][2]); pk.w = f2bf(acc[i][j][3]);
        *reinterpret_cast<ushort4*>(&VpT[(size_t)(b * 1024 + col) * 2048 + s]) = pk;
      }
  }
}

__global__ __launch_bounds__(256) void gemm_out(
    const unsigned short* __restrict__ Xp, const unsigned short* __restrict__ Wo,
    float* __restrict__ out) {
  __shared__ __align__(16) unsigned short As[128 * 32];
  __shared__ __align__(16) unsigned short Bs[128 * 32];
  const int tileM = blockIdx.x * 128, tileN = blockIdx.y * 128;
  f32x4 acc[4][4];
  gemm_core(Xp, Wo, As, Bs, acc, tileM, tileN);
  const int tid = threadIdx.x, w = tid >> 6, lane = tid & 63;
  const int wr = (w & 1) * 64, wc = (w >> 1) * 64;
  const int l15 = lane & 15, g4 = lane >> 4;
#pragma unroll
  for (int i = 0; i < 4; i++)
#pragma unroll
    for (int j = 0; j < 4; j++) {
      int col = tileN + wc + j * 16 + l15;
#pragma unroll
      for (int r = 0; r < 4; r++) {
        int row = tileM + wr + i * 16 + g4 * 4 + r;
        out[(size_t)row * 1024 + col] = acc[i][j][r];
      }
    }
}

// ---- Flash attention: one block per (q-tile of 64, b*h). 4 waves, each owns
// 16 q rows. K/V tiles of 64. Qp/Kp: [8192,1024] bf16. VpT: [4096,2048] bf16.
__global__ __launch_bounds__(256) void attn(
    const unsigned short* __restrict__ Qp, const unsigned short* __restrict__ Kp,
    const unsigned short* __restrict__ VpT, unsigned short* __restrict__ Xp) {
  __shared__ __align__(16) unsigned short Ks[64 * 64];   // [kpos][d]
  __shared__ __align__(16) unsigned short Vs[64 * 64];   // transposed: [d][kpos]
  __shared__ __align__(16) unsigned short Ps[4 * 16 * 64];  // per-wave P

  const int bh = blockIdx.y, b = bh >> 4, h = bh & 15;
  const int q0 = blockIdx.x * 64;
  const int tid = threadIdx.x, w = tid >> 6, lane = tid & 63;
  const int l15 = lane & 15, g4 = lane >> 4;

  // Q fragments (A-operand layout): rows q0+w*16+l15, k = g4*8 (+32)
  const unsigned short* Qrow =
      Qp + (size_t)(b * 2048 + q0 + w * 16 + l15) * 1024 + h * 64;
  const bf16x8 qf0 = *reinterpret_cast<const bf16x8*>(Qrow + g4 * 8);
  const bf16x8 qf1 = *reinterpret_cast<const bf16x8*>(Qrow + 32 + g4 * 8);

  const f32x4 fzero = {0.f, 0.f, 0.f, 0.f};
  f32x4 o[4] = {fzero, fzero, fzero, fzero};
  float m_i[4] = {-INFINITY, -INFINITY, -INFINITY, -INFINITY};
  float l_i[4] = {0.f, 0.f, 0.f, 0.f};

  const unsigned short* Kbase = Kp + (size_t)(b * 2048) * 1024 + h * 64;
  const unsigned short* Vbase = VpT + (size_t)(b * 1024 + h * 64) * 2048;
  unsigned short* Pw = Ps + w * 1024;

  for (int kt = 0; kt < 2048; kt += 64) {
#pragma unroll
    for (int j = 0; j < 2; ++j) {
      int c = w * 2 + j;  // 8 rows x 128B per chunk
      ld16(Kbase + (size_t)(kt + c * 8 + (lane >> 3)) * 1024 + (lane & 7) * 8,
           Ks + c * 512);
      ld16(Vbase + (size_t)(c * 8 + (lane >> 3)) * 2048 + kt + (lane & 7) * 8,
           Vs + c * 512);
    }
    __syncthreads();

    // S = Q K^T / 8   (16 q rows x 64 kpos per wave)
    f32x4 sv[4];
#pragma unroll
    for (int j = 0; j < 4; j++) {
      bf16x8 kf0 = *reinterpret_cast<const bf16x8*>(&Ks[(j * 16 + l15) * 64 + g4 * 8]);
      bf16x8 kf1 = *reinterpret_cast<const bf16x8*>(&Ks[(j * 16 + l15) * 64 + 32 + g4 * 8]);
      f32x4 z = fzero;
      z = __builtin_amdgcn_mfma_f32_16x16x32_bf16(qf0, kf0, z, 0, 0, 0);
      z = __builtin_amdgcn_mfma_f32_16x16x32_bf16(qf1, kf1, z, 0, 0, 0);
      sv[j] = z * 0.125f;
    }

    // online softmax: rows m = g4*4 + r, cols spread over l15 and j
    float mx[4], al[4], rs[4];
#pragma unroll
    for (int r = 0; r < 4; r++) {
      mx[r] = fmaxf(fmaxf(sv[0][r], sv[1][r]), fmaxf(sv[2][r], sv[3][r]));
#pragma unroll
      for (int off = 1; off < 16; off <<= 1)
        mx[r] = fmaxf(mx[r], __shfl_xor(mx[r], off));
      float mn = fmaxf(m_i[r], mx[r]);
      al[r] = __expf(m_i[r] - mn);  // -inf - finite = -inf -> 0 on first tile
      m_i[r] = mn;
    }
#pragma unroll
    for (int j = 0; j < 4; j++)
#pragma unroll
      for (int r = 0; r < 4; r++) sv[j][r] = __expf(sv[j][r] - m_i[r]);
#pragma unroll
    for (int r = 0; r < 4; r++) {
      rs[r] = sv[0][r] + sv[1][r] + sv[2][r] + sv[3][r];
#pragma unroll
      for (int off = 1; off < 16; off <<= 1) rs[r] += __shfl_xor(rs[r], off);
      l_i[r] = l_i[r] * al[r] + rs[r];
    }
#pragma unroll
    for (int dj = 0; dj < 4; dj++) {
      o[dj][0] *= al[0]; o[dj][1] *= al[1]; o[dj][2] *= al[2]; o[dj][3] *= al[3];
    }

    // P: C-layout -> LDS -> A-layout (per-wave buffer, in-order DS, no barrier)
#pragma unroll
    for (int j = 0; j < 4; j++)
#pragma unroll
      for (int r = 0; r < 4; r++)
        Pw[(g4 * 4 + r) * 64 + j * 16 + l15] = f2bf(sv[j][r]);

    // O += P V : A = P [16 x 64kpos], B = V [kpos][d] = Vs[d][kpos]
#pragma unroll
    for (int kc = 0; kc < 2; kc++) {
      bf16x8 pf = *reinterpret_cast<const bf16x8*>(&Pw[l15 * 64 + kc * 32 + g4 * 8]);
#pragma unroll
      for (int dj = 0; dj < 4; dj++) {
        bf16x8 vf = *reinterpret_cast<const bf16x8*>(
            &Vs[(dj * 16 + l15) * 64 + kc * 32 + g4 * 8]);
        o[dj] = __builtin_amdgcn_mfma_f32_16x16x32_bf16(pf, vf, o[dj], 0, 0, 0);
      }
    }
    __syncthreads();
  }

  float inv[4];
#pragma unroll
  for (int r = 0; r < 4; r++) inv[r] = 1.f / l_i[r];
#pragma unroll
  for (int dj = 0; dj < 4; dj++)
#pragma unroll
    for (int r = 0; r < 4; r++) {
      int row = b * 2048 + q0 + w * 16 + g4 * 4 + r;
      Xp[(size_t)row * 1024 + h * 64 + dj * 16 + l15] = f2bf(o[dj][r] * inv[r]);
    }
}

extern "C" void kernel_launch(void* const* d_in, const int* in_sizes, int n_in,
                              void* d_out, int out_size, void* d_ws, size_t ws_size,
                              hipStream_t stream) {
  const float* q  = (const float*)d_in[0];
  const float* k  = (const float*)d_in[1];
  const float* v  = (const float*)d_in[2];
  // d_in[3] mask: unused by the reference
  const float* Wq = (const float*)d_in[4];
  const float* Wk = (const float*)d_in[5];
  const float* Wv = (const float*)d_in[6];
  const float* Wo = (const float*)d_in[7];
  float* out = (float*)d_out;

  char* ws = (char*)d_ws;
  const size_t MB = 1u << 20;
  unsigned short* qb  = (unsigned short*)(ws + 0 * MB);    // 16 MB each
  unsigned short* kb  = (unsigned short*)(ws + 16 * MB);
  unsigned short* vb  = (unsigned short*)(ws + 32 * MB);
  unsigned short* wqb = (unsigned short*)(ws + 48 * MB);   // 2 MB each
  unsigned short* wkb = (unsigned short*)(ws + 50 * MB);
  unsigned short* wvb = (unsigned short*)(ws + 52 * MB);
  unsigned short* wob = (unsigned short*)(ws + 54 * MB);
  unsigned short* Qp  = (unsigned short*)(ws + 56 * MB);   // 16 MB
  unsigned short* Kp  = (unsigned short*)(ws + 72 * MB);   // 16 MB
  unsigned short* VpT = (unsigned short*)(ws + 88 * MB);   // 16 MB, [B*1024, 2048]
  unsigned short* Xp  = (unsigned short*)(ws + 104 * MB);  // 16 MB

  const int n4_t = (4 * 2048 * 1024) / 4;  // 2097152 -> 8192 blocks
  const int n4_w = (1024 * 1024) / 4;      // 262144  -> 1024 blocks
  cast_f32_bf16<<<n4_t / 256, 256, 0, stream>>>(q, qb, n4_t);
  cast_f32_bf16<<<n4_t / 256, 256, 0, stream>>>(k, kb, n4_t);
  cast_f32_bf16<<<n4_t / 256, 256, 0, stream>>>(v, vb, n4_t);
  cast_f32_bf16<<<n4_w / 256, 256, 0, stream>>>(Wq, wqb, n4_w);
  cast_f32_bf16<<<n4_w / 256, 256, 0, stream>>>(Wk, wkb, n4_w);
  cast_f32_bf16<<<n4_w / 256, 256, 0, stream>>>(Wv, wvb, n4_w);
  cast_f32_bf16<<<n4_w / 256, 256, 0, stream>>>(Wo, wob, n4_w);

  dim3 gq(64, 8, 3);
  gemm_qkv<<<gq, 256, 0, stream>>>(qb, kb, vb, wqb, wkb, wvb, Qp, Kp, VpT);

  dim3 ga(32, 64);  // (S/64, B*H)
  attn<<<ga, 256, 0, stream>>>(Qp, Kp, VpT, Xp);

  dim3 go(64, 8, 1);
  gemm_out<<<go, 256, 0, stream>>>(Xp, wob, out);
}

// Round 2
// 428.690 us; speedup vs baseline: 1.2701x; 1.2701x over previous
//
#include <hip/hip_runtime.h>
#include <math.h>

// Problem: B=4, S=2048, D=1024, H=16, DK=64.
// out = softmax((q Wq^T)(k Wk^T)^T / 8) (v Wv^T) Wo^T, heads split on D.
//
// Pipeline:
//   1. cast fp32->bf16: q,k,v, Wq,Wk,Wv,Wo              (ws)
//   2. gemm_qkv: Qp=(q@Wq^T)*0.125, Kp=k@Wk^T (bf16 [8192,1024]),
//                VpT = (v@Wv^T) stored transposed [B*1024, 2048] bf16
//   3. attn: flash attention, S^T/O^T formulation, Q-tile 128, K-tile 64,
//            XOR-swizzled LDS (bank-conflict-free) -> Xp bf16
//   4. gemm_out: out = Xp @ Wo^T  (fp32)

#define DEV __device__ __forceinline__

typedef __bf16 bf16x8 __attribute__((ext_vector_type(8)));
typedef float f32x4 __attribute__((ext_vector_type(4)));
typedef unsigned int u32x2 __attribute__((ext_vector_type(2)));

typedef __attribute__((address_space(1))) const unsigned int g_u32;
typedef __attribute__((address_space(3))) unsigned int l_u32;

DEV unsigned short f2bf(float x) {  // RNE truncate to bf16
  unsigned int u = __float_as_uint(x);
  u += 0x7fffu + ((u >> 16) & 1u);
  return (unsigned short)(u >> 16);
}

DEV unsigned int pack2bf(float a, float b) {
  return (unsigned int)f2bf(a) | ((unsigned int)f2bf(b) << 16);
}

DEV void ld16(const unsigned short* g, unsigned short* l) {
  // async global->LDS, 16B per lane; LDS dest = wave-uniform base + lane*16
  __builtin_amdgcn_global_load_lds((g_u32*)g, (l_u32*)l, 16, 0, 0);
}

__global__ __launch_bounds__(256) void cast_f32_bf16(
    const float* __restrict__ src, unsigned short* __restrict__ dst, int n4) {
  int i = blockIdx.x * 256 + threadIdx.x;
  if (i < n4) {
    float4 v = reinterpret_cast<const float4*>(src)[i];
    ushort4 o;
    o.x = f2bf(v.x); o.y = f2bf(v.y); o.z = f2bf(v.z); o.w = f2bf(v.w);
    reinterpret_cast<ushort4*>(dst)[i] = o;
  }
}

// ---- NT GEMM core: C[128x128] tile, A [M,1024] bf16 rm, W [N,1024] bf16 rm.
// 4 waves, each 64x64 (4x4 MFMA tiles of 16x16x32 bf16). BK=32.
DEV void gemm_core(const unsigned short* __restrict__ A,
                   const unsigned short* __restrict__ W,
                   unsigned short* As, unsigned short* Bs,
                   f32x4 (&acc)[4][4], int tileM, int tileN) {
  const int tid = threadIdx.x;
  const int w = tid >> 6, lane = tid & 63;
  const int wr = (w & 1) * 64, wc = (w >> 1) * 64;
  const int l15 = lane & 15, g4 = lane >> 4;
  const int srow = lane >> 2;        // staging: 4 lanes per 32-elem row
  const int scol = (lane & 3) * 8;

  const f32x4 fzero = {0.f, 0.f, 0.f, 0.f};
#pragma unroll
  for (int i = 0; i < 4; i++)
#pragma unroll
    for (int j = 0; j < 4; j++) acc[i][j] = fzero;

  for (int k0 = 0; k0 < 1024; k0 += 32) {
#pragma unroll
    for (int j = 0; j < 2; ++j) {
      int c = w * 2 + j;  // chunk: 16 rows x 64B = 1024B
      ld16(A + (size_t)(tileM + c * 16 + srow) * 1024 + k0 + scol, As + c * 512);
      ld16(W + (size_t)(tileN + c * 16 + srow) * 1024 + k0 + scol, Bs + c * 512);
    }
    __syncthreads();
    bf16x8 aF[4], bF[4];
#pragma unroll
    for (int i = 0; i < 4; i++)
      aF[i] = *reinterpret_cast<const bf16x8*>(&As[(wr + i * 16 + l15) * 32 + g4 * 8]);
#pragma unroll
    for (int j = 0; j < 4; j++)
      bF[j] = *reinterpret_cast<const bf16x8*>(&Bs[(wc + j * 16 + l15) * 32 + g4 * 8]);
#pragma unroll
    for (int i = 0; i < 4; i++)
#pragma unroll
      for (int j = 0; j < 4; j++)
        acc[i][j] = __builtin_amdgcn_mfma_f32_16x16x32_bf16(aF[i], bF[j], acc[i][j], 0, 0, 0);
    __syncthreads();
  }
}

__global__ __launch_bounds__(256) void gemm_qkv(
    const unsigned short* __restrict__ qb, const unsigned short* __restrict__ kb,
    const unsigned short* __restrict__ vb, const unsigned short* __restrict__ Wq,
    const unsigned short* __restrict__ Wk, const unsigned short* __restrict__ Wv,
    unsigned short* __restrict__ Qp, unsigned short* __restrict__ Kp,
    unsigned short* __restrict__ VpT) {
  __shared__ __align__(16) unsigned short As[128 * 32];
  __shared__ __align__(16) unsigned short Bs[128 * 32];
  const int z = blockIdx.z;
  const unsigned short* A = (z == 0) ? qb : (z == 1) ? kb : vb;
  const unsigned short* W = (z == 0) ? Wq : (z == 1) ? Wk : Wv;
  const int tileM = blockIdx.x * 128, tileN = blockIdx.y * 128;
  f32x4 acc[4][4];
  gemm_core(A, W, As, Bs, acc, tileM, tileN);

  const int tid = threadIdx.x, w = tid >> 6, lane = tid & 63;
  const int wr = (w & 1) * 64, wc = (w >> 1) * 64;
  const int l15 = lane & 15, g4 = lane >> 4;
  if (z < 2) {
    // fold the 1/sqrt(DK)=0.125 score scale into Q (exact: power of 2)
    const float qs = (z == 0) ? 0.125f : 1.0f;
    unsigned short* C = (z == 0) ? Qp : Kp;
#pragma unroll
    for (int i = 0; i < 4; i++)
#pragma unroll
      for (int j = 0; j < 4; j++) {
        int col = tileN + wc + j * 16 + l15;
#pragma unroll
        for (int r = 0; r < 4; r++) {
          int row = tileM + wr + i * 16 + g4 * 4 + r;
          C[(size_t)row * 1024 + col] = f2bf(acc[i][j][r] * qs);
        }
      }
  } else {
    // transposed store: VpT[(b*1024 + col)*2048 + s], 4 contiguous s per lane
    const int b = tileM / 2048, s0 = tileM % 2048;
#pragma unroll
    for (int i = 0; i < 4; i++)
#pragma unroll
      for (int j = 0; j < 4; j++) {
        int col = tileN + wc + j * 16 + l15;
        int s = s0 + wr + i * 16 + g4 * 4;
        ushort4 pk;
        pk.x = f2bf(acc[i][j][0]); pk.y = f2bf(acc[i][j][1]);
        pk.z = f2bf(acc[i][j][2]); pk.w = f2bf(acc[i][j][3]);
        *reinterpret_cast<ushort4*>(&VpT[(size_t)(b * 1024 + col) * 2048 + s]) = pk;
      }
  }
}

__global__ __launch_bounds__(256) void gemm_out(
    const unsigned short* __restrict__ Xp, const unsigned short* __restrict__ Wo,
    float* __restrict__ out) {
  __shared__ __align__(16) unsigned short As[128 * 32];
  __shared__ __align__(16) unsigned short Bs[128 * 32];
  const int tileM = blockIdx.x * 128, tileN = blockIdx.y * 128;
  f32x4 acc[4][4];
  gemm_core(Xp, Wo, As, Bs, acc, tileM, tileN);
  const int tid = threadIdx.x, w = tid >> 6, lane = tid & 63;
  const int wr = (w & 1) * 64, wc = (w >> 1) * 64;
  const int l15 = lane & 15, g4 = lane >> 4;
#pragma unroll
  for (int i = 0; i < 4; i++)
#pragma unroll
    for (int j = 0; j < 4; j++) {
      int col = tileN + wc + j * 16 + l15;
#pragma unroll
      for (int r = 0; r < 4; r++) {
        int row = tileM + wr + i * 16 + g4 * 4 + r;
        out[(size_t)row * 1024 + col] = acc[i][j][r];
      }
    }
}

// ---- Flash attention, S^T/O^T formulation.
// Block: 4 waves, Q-tile 128 (32 q-rows/wave = 2 m-tiles), K/V-tile 64.
// S^T = K·Q^T via mfma(kf,qf): C-layout col=l15=m(q row), row=g4*4+r=kp.
// Softmax state (m,l,alpha) is per-lane scalar (replicated over g4).
// O^T += V^T·P^T via mfma(vf,pf): col=l15=m, row=d.
// All LDS tiles XOR-swizzled (granule ^ row) -> bank-even b128/b64 access.
// Qp is pre-scaled by 0.125 so no score scaling here.
__global__ __launch_bounds__(256, 4) void attn(
    const unsigned short* __restrict__ Qp, const unsigned short* __restrict__ Kp,
    const unsigned short* __restrict__ VpT, unsigned short* __restrict__ Xp) {
  __shared__ __align__(16) unsigned short Ks[64 * 64];      // [kp][d], 16B-gran swz
  __shared__ __align__(16) unsigned short Vs[64 * 64];      // [d][kp], 16B-gran swz
  __shared__ __align__(16) unsigned short Ps[4 * 32 * 64];  // per-wave P[m][kp], 8B-gran swz

  const int bh = blockIdx.y, b = bh >> 4, h = bh & 15;
  const int q0 = blockIdx.x * 128;
  const int tid = threadIdx.x, w = tid >> 6, lane = tid & 63;
  const int l15 = lane & 15, g4 = lane >> 4;
  const int l7 = l15 & 7;

  // staging address permutation (compensates forced lane-contiguous LDS dest)
  const int rsub = lane >> 3;               // row within 8-row chunk
  const int gsrc = (lane & 7) ^ rsub;       // swizzled source granule

  // Q fragments: rows q0 + w*32 + mi*16 + l15, k = half*32 + g4*8
  bf16x8 qf[2][2];
#pragma unroll
  for (int mi = 0; mi < 2; mi++) {
    const unsigned short* Qrow =
        Qp + (size_t)(b * 2048 + q0 + w * 32 + mi * 16 + l15) * 1024 + h * 64;
    qf[mi][0] = *reinterpret_cast<const bf16x8*>(Qrow + g4 * 8);
    qf[mi][1] = *reinterpret_cast<const bf16x8*>(Qrow + 32 + g4 * 8);
  }

  const f32x4 fzero = {0.f, 0.f, 0.f, 0.f};
  f32x4 o[2][4];
#pragma unroll
  for (int mi = 0; mi < 2; mi++)
#pragma unroll
    for (int dj = 0; dj < 4; dj++) o[mi][dj] = fzero;
  float m_i[2] = {-INFINITY, -INFINITY};
  float l_i[2] = {0.f, 0.f};

  const unsigned short* Kbase = Kp + (size_t)(b * 2048) * 1024 + h * 64;
  const unsigned short* Vbase = VpT + (size_t)(b * 1024 + h * 64) * 2048;
  unsigned short* Pw = Ps + w * 2048;

  for (int kt = 0; kt < 2048; kt += 64) {
#pragma unroll
    for (int j = 0; j < 2; ++j) {
      int c = w * 2 + j;  // 8 rows x 128B per chunk, granule-permuted source
      ld16(Kbase + (size_t)(kt + c * 8 + rsub) * 1024 + gsrc * 8, Ks + c * 512);
      ld16(Vbase + (size_t)(c * 8 + rsub) * 2048 + kt + gsrc * 8, Vs + c * 512);
    }
    __syncthreads();

    // S^T = K Q^T : sv[mi][jt][r] = S[m=mi*16+l15][kp = kt + jt*16 + g4*4 + r]
    f32x4 sv[2][4];
#pragma unroll
    for (int jt = 0; jt < 4; jt++) {
      const int row = jt * 16 + l15;
      const int s0 = g4 ^ l7;
      bf16x8 kf0 = *reinterpret_cast<const bf16x8*>(&Ks[row * 64 + s0 * 8]);
      bf16x8 kf1 = *reinterpret_cast<const bf16x8*>(&Ks[row * 64 + (s0 ^ 4) * 8]);
#pragma unroll
      for (int mi = 0; mi < 2; mi++) {
        f32x4 z = fzero;
        z = __builtin_amdgcn_mfma_f32_16x16x32_bf16(kf0, qf[mi][0], z, 0, 0, 0);
        z = __builtin_amdgcn_mfma_f32_16x16x32_bf16(kf1, qf[mi][1], z, 0, 0, 0);
        sv[mi][jt] = z;
      }
    }

    // online softmax (row stats per-lane scalar; row m = mi*16 + l15)
#pragma unroll
    for (int mi = 0; mi < 2; mi++) {
      float mx = sv[mi][0][0];
#pragma unroll
      for (int jt = 0; jt < 4; jt++)
#pragma unroll
        for (int r = 0; r < 4; r++) mx = fmaxf(mx, sv[mi][jt][r]);
      mx = fmaxf(mx, __shfl_xor(mx, 16));
      mx = fmaxf(mx, __shfl_xor(mx, 32));
      float mn = fmaxf(m_i[mi], mx);
      float al = __expf(m_i[mi] - mn);  // -inf on first tile -> 0
      m_i[mi] = mn;
      float rs = 0.f;
#pragma unroll
      for (int jt = 0; jt < 4; jt++) {
#pragma unroll
        for (int r = 0; r < 4; r++) {
          sv[mi][jt][r] = __expf(sv[mi][jt][r] - mn);
          rs += sv[mi][jt][r];
        }
      }
      rs += __shfl_xor(rs, 16);
      rs += __shfl_xor(rs, 32);
      l_i[mi] = l_i[mi] * al + rs;
#pragma unroll
      for (int dj = 0; dj < 4; dj++) o[mi][dj] *= al;

      // P write: 4 consecutive kp per lane -> b64, 8B-granule swizzle
      const int prow = mi * 16 + l15;
#pragma unroll
      for (int jt = 0; jt < 4; jt++) {
        u32x2 pk;
        pk.x = pack2bf(sv[mi][jt][0], sv[mi][jt][1]);
        pk.y = pack2bf(sv[mi][jt][2], sv[mi][jt][3]);
        const int slot = (jt * 4 + g4) ^ l15;
        *reinterpret_cast<u32x2*>(&Pw[prow * 64 + slot * 4]) = pk;
      }
    }

    // O^T += V^T P^T
#pragma unroll
    for (int kc = 0; kc < 2; kc++) {
      bf16x8 vf[4];
#pragma unroll
      for (int dj = 0; dj < 4; dj++) {
        const int row = dj * 16 + l15;
        const int sg = (kc * 4 + g4) ^ l7;
        vf[dj] = *reinterpret_cast<const bf16x8*>(&Vs[row * 64 + sg * 8]);
      }
#pragma unroll
      for (int mi = 0; mi < 2; mi++) {
        const int prow = mi * 16 + l15;
        const int sA = (kc * 8 + g4 * 2) ^ l15;
        const int sB = (kc * 8 + g4 * 2 + 1) ^ l15;
        u32x2 pa = *reinterpret_cast<const u32x2*>(&Pw[prow * 64 + sA * 4]);
        u32x2 pb = *reinterpret_cast<const u32x2*>(&Pw[prow * 64 + sB * 4]);
        union { unsigned int u[4]; bf16x8 v; } pf;
        pf.u[0] = pa.x; pf.u[1] = pa.y; pf.u[2] = pb.x; pf.u[3] = pb.y;
#pragma unroll
        for (int dj = 0; dj < 4; dj++)
          o[mi][dj] = __builtin_amdgcn_mfma_f32_16x16x32_bf16(vf[dj], pf.v, o[mi][dj], 0, 0, 0);
      }
    }
    __syncthreads();
  }

  // epilogue: O^T C-layout col=l15=m, row=dj*16+g4*4+r -> ushort4 stores
#pragma unroll
  for (int mi = 0; mi < 2; mi++) {
    const float inv = 1.f / l_i[mi];
    const size_t row = (size_t)(b * 2048 + q0 + w * 32 + mi * 16 + l15);
#pragma unroll
    for (int dj = 0; dj < 4; dj++) {
      ushort4 pk;
      pk.x = f2bf(o[mi][dj][0] * inv);
      pk.y = f2bf(o[mi][dj][1] * inv);
      pk.z = f2bf(o[mi][dj][2] * inv);
      pk.w = f2bf(o[mi][dj][3] * inv);
      *reinterpret_cast<ushort4*>(&Xp[row * 1024 + h * 64 + dj * 16 + g4 * 4]) = pk;
    }
  }
}

extern "C" void kernel_launch(void* const* d_in, const int* in_sizes, int n_in,
                              void* d_out, int out_size, void* d_ws, size_t ws_size,
                              hipStream_t stream) {
  const float* q  = (const float*)d_in[0];
  const float* k  = (const float*)d_in[1];
  const float* v  = (const float*)d_in[2];
  // d_in[3] mask: unused by the reference
  const float* Wq = (const float*)d_in[4];
  const float* Wk = (const float*)d_in[5];
  const float* Wv = (const float*)d_in[6];
  const float* Wo = (const float*)d_in[7];
  float* out = (float*)d_out;

  char* ws = (char*)d_ws;
  const size_t MB = 1u << 20;
  unsigned short* qb  = (unsigned short*)(ws + 0 * MB);    // 16 MB each
  unsigned short* kb  = (unsigned short*)(ws + 16 * MB);
  unsigned short* vb  = (unsigned short*)(ws + 32 * MB);
  unsigned short* wqb = (unsigned short*)(ws + 48 * MB);   // 2 MB each
  unsigned short* wkb = (unsigned short*)(ws + 50 * MB);
  unsigned short* wvb = (unsigned short*)(ws + 52 * MB);
  unsigned short* wob = (unsigned short*)(ws + 54 * MB);
  unsigned short* Qp  = (unsigned short*)(ws + 56 * MB);   // 16 MB (pre-scaled 1/8)
  unsigned short* Kp  = (unsigned short*)(ws + 72 * MB);   // 16 MB
  unsigned short* VpT = (unsigned short*)(ws + 88 * MB);   // 16 MB, [B*1024, 2048]
  unsigned short* Xp  = (unsigned short*)(ws + 104 * MB);  // 16 MB

  const int n4_t = (4 * 2048 * 1024) / 4;
  const int n4_w = (1024 * 1024) / 4;
  cast_f32_bf16<<<n4_t / 256, 256, 0, stream>>>(q, qb, n4_t);
  cast_f32_bf16<<<n4_t / 256, 256, 0, stream>>>(k, kb, n4_t);
  cast_f32_bf16<<<n4_t / 256, 256, 0, stream>>>(v, vb, n4_t);
  cast_f32_bf16<<<n4_w / 256, 256, 0, stream>>>(Wq, wqb, n4_w);
  cast_f32_bf16<<<n4_w / 256, 256, 0, stream>>>(Wk, wkb, n4_w);
  cast_f32_bf16<<<n4_w / 256, 256, 0, stream>>>(Wv, wvb, n4_w);
  cast_f32_bf16<<<n4_w / 256, 256, 0, stream>>>(Wo, wob, n4_w);

  dim3 gq(64, 8, 3);
  gemm_qkv<<<gq, 256, 0, stream>>>(qb, kb, vb, wqb, wkb, wvb, Qp, Kp, VpT);

  dim3 ga(16, 64);  // (S/128, B*H)
  attn<<<ga, 256, 0, stream>>>(Qp, Kp, VpT, Xp);

  dim3 go(64, 8, 1);
  gemm_out<<<go, 256, 0, stream>>>(Xp, wob, out);
}